// Round 1
// baseline (963.104 us; speedup 1.0000x reference)
//
#include <hip/hip_runtime.h>
#include <hip/hip_bf16.h>

#define NN 100000
#define NE 1600000
#define D 128
#define K3 384
#define LN_EPS 1e-5f
#define TILE_N 16
#define KC 64

// ---- workspace layout (bytes, 256-aligned) ----
// off  : (NN+1) int          @ 0        (400004 -> 400128)
// cnt  : NN int              @ 400128
// cur  : NN int              @ 800256
// esrc : NE int              @ 1200384  (6400000)
// wc   : 128*384 float       @ 7600384  (196608)
// nb2  : NN*128 bf16(ushort) @ 7796992  (25600000)
#define WS_OFF_OFF  0
#define WS_OFF_CNT  400128
#define WS_OFF_CUR  800256
#define WS_OFF_ESRC 1200384
#define WS_OFF_WC   7600384
#define WS_OFF_NB2  7796992

__device__ __forceinline__ unsigned short f2bf(float f) {
    unsigned u = __float_as_uint(f);
    unsigned r = (u + 0x7FFFu + ((u >> 16) & 1u)) >> 16;
    return (unsigned short)r;
}
__device__ __forceinline__ float bf2f(unsigned short b) {
    return __uint_as_float(((unsigned)b) << 16);
}

__global__ void k_count(const int* __restrict__ dst, int* __restrict__ cnt) {
    int e = blockIdx.x * blockDim.x + threadIdx.x;
    if (e < NE) atomicAdd(&cnt[dst[e]], 1);
}

__global__ void k_scan(const int* __restrict__ cnt, int* __restrict__ off) {
    __shared__ int lds[1024];
    const int CH = 98; // 1024*98 >= NN
    int t = threadIdx.x;
    int lo = t * CH;
    int hi = lo + CH; if (hi > NN) hi = NN;
    int s = 0;
    for (int i = lo; i < hi; ++i) s += cnt[i];
    lds[t] = s;
    __syncthreads();
    for (int ofs = 1; ofs < 1024; ofs <<= 1) {
        int v = (t >= ofs) ? lds[t - ofs] : 0;
        __syncthreads();
        lds[t] += v;
        __syncthreads();
    }
    int run = (t == 0) ? 0 : lds[t - 1];
    for (int i = lo; i < hi; ++i) { off[i] = run; run += cnt[i]; }
    if (t == 0) off[NN] = lds[1023];
}

__global__ void k_scatter(const int* __restrict__ src, const int* __restrict__ dst,
                          const int* __restrict__ off, int* __restrict__ cur,
                          int* __restrict__ esrc) {
    int e = blockIdx.x * blockDim.x + threadIdx.x;
    if (e < NE) {
        int d = dst[e];
        int p = off[d] + atomicAdd(&cur[d], 1);
        esrc[p] = src[e];
    }
}

__global__ void k_weights(const float* __restrict__ Ws, const float* __restrict__ W1,
                          const float* __restrict__ Whp, const float* __restrict__ W2,
                          const float* __restrict__ logits, float* __restrict__ wc) {
    int idx = blockIdx.x * blockDim.x + threadIdx.x;
    if (idx >= D * D) return;
    int o = idx >> 7, k = idx & 127;
    float s0 = 2.f / (1.f + __expf(-logits[0]));
    float s1 = 2.f / (1.f + __expf(-logits[1]));
    float s2 = 2.f / (1.f + __expf(-logits[2]));
    float s3 = 2.f / (1.f + __expf(-logits[3]));
    float wself = Ws[idx], wnb1 = W1[idx], whp = Whp[idx], wnb2 = W2[idx];
    wc[(size_t)o * K3 + k]       = s0 * wself + s2 * whp;
    wc[(size_t)o * K3 + 128 + k] = s1 * wnb1 - s2 * whp;
    wc[(size_t)o * K3 + 256 + k] = s3 * wnb2;
}

// one wave per node; lane owns 2 dims (float2). OUT_BF16: pack to bf16 bits.
template <bool OUT_BF16>
__global__ void k_hop(const float* __restrict__ in, void* __restrict__ outv,
                      const int* __restrict__ off, const int* __restrict__ esrc,
                      const float* __restrict__ deg) {
    int w = (blockIdx.x * blockDim.x + threadIdx.x) >> 6;
    int lane = threadIdx.x & 63;
    if (w >= NN) return;
    int beg = __builtin_amdgcn_readfirstlane(off[w]);
    int end = __builtin_amdgcn_readfirstlane(off[w + 1]);
    float ax = 0.f, ay = 0.f;
    int j = beg;
    for (; j + 1 < end; j += 2) {
        int s0 = __builtin_amdgcn_readfirstlane(esrc[j]);
        int s1 = __builtin_amdgcn_readfirstlane(esrc[j + 1]);
        const float2 v0 = *reinterpret_cast<const float2*>(in + (size_t)s0 * D + lane * 2);
        const float2 v1 = *reinterpret_cast<const float2*>(in + (size_t)s1 * D + lane * 2);
        ax += v0.x + v1.x;
        ay += v0.y + v1.y;
    }
    if (j < end) {
        int s0 = __builtin_amdgcn_readfirstlane(esrc[j]);
        const float2 v0 = *reinterpret_cast<const float2*>(in + (size_t)s0 * D + lane * 2);
        ax += v0.x;
        ay += v0.y;
    }
    float inv = 1.0f / deg[w];
    ax *= inv; ay *= inv;
    if (OUT_BF16) {
        ushort2 p; p.x = f2bf(ax); p.y = f2bf(ay);
        reinterpret_cast<ushort2*>(outv)[(size_t)w * (D / 2) + lane] = p;
    } else {
        float2 p; p.x = ax; p.y = ay;
        reinterpret_cast<float2*>(outv)[(size_t)w * (D / 2) + lane] = p;
    }
}

union EpU {
    float wct[KC][129];      // transposed W chunk: wct[kk][o]
    float zs[TILE_N][129];   // epilogue z values
};

__global__ __launch_bounds__(256) void k_gemm_ln(
    const float* __restrict__ h, const float* __restrict__ nb1,
    const unsigned short* __restrict__ nb2, const float* __restrict__ wc,
    const float* __restrict__ bias, const float* __restrict__ gamma,
    const float* __restrict__ beta, float* __restrict__ out) {
    __shared__ float Xt[K3][20];   // Xt[k][node], pad 20 keeps float4 rows 16B-aligned
    __shared__ EpU u;
    __shared__ float mu_s[TILE_N], rs_s[TILE_N];

    const int t = threadIdx.x;
    const int node0 = blockIdx.x * TILE_N;

    // ---- stage X (h | nb1 | nb2) transposed into LDS ----
    for (int srci = 0; srci < 2; ++srci) {
        const float* sp = srci ? nb1 : h;
        int koff = srci * 128;
        #pragma unroll
        for (int it = 0; it < 2; ++it) {
            int i = t + 256 * it;        // 0..511
            int n = i >> 5, k4 = i & 31;
            const float4 v = *reinterpret_cast<const float4*>(sp + (size_t)(node0 + n) * D + k4 * 4);
            Xt[koff + k4 * 4 + 0][n] = v.x;
            Xt[koff + k4 * 4 + 1][n] = v.y;
            Xt[koff + k4 * 4 + 2][n] = v.z;
            Xt[koff + k4 * 4 + 3][n] = v.w;
        }
    }
    #pragma unroll
    for (int it = 0; it < 2; ++it) {
        int i = t + 256 * it;
        int n = i >> 5, k4 = i & 31;
        const ushort4 v = *(reinterpret_cast<const ushort4*>(nb2 + (size_t)(node0 + n) * D) + k4);
        Xt[256 + k4 * 4 + 0][n] = bf2f(v.x);
        Xt[256 + k4 * 4 + 1][n] = bf2f(v.y);
        Xt[256 + k4 * 4 + 2][n] = bf2f(v.z);
        Xt[256 + k4 * 4 + 3][n] = bf2f(v.w);
    }

    const int o_t = t & 127;
    const int half = t >> 7;     // wave-uniform (waves 0,1 -> 0; waves 2,3 -> 1)
    float acc[8];
    {
        float b = bias[o_t];
        #pragma unroll
        for (int j = 0; j < 8; ++j) acc[j] = b;
    }

    for (int c = 0; c < K3 / KC; ++c) {
        __syncthreads();  // Xt ready (first iter) / wct no longer read (later iters)
        // stage transposed W chunk: wct[kk][o] = wc[o][c*KC+kk]
        #pragma unroll
        for (int it = 0; it < 8; ++it) {
            int i = t + 256 * it;        // 0..2047 float4 groups
            int o = i >> 4, kk4 = i & 15;
            const float4 v = *reinterpret_cast<const float4*>(wc + (size_t)o * K3 + c * KC + kk4 * 4);
            u.wct[kk4 * 4 + 0][o] = v.x;
            u.wct[kk4 * 4 + 1][o] = v.y;
            u.wct[kk4 * 4 + 2][o] = v.z;
            u.wct[kk4 * 4 + 3][o] = v.w;
        }
        __syncthreads();
        #pragma unroll
        for (int kk = 0; kk < KC; ++kk) {
            float w = u.wct[kk][o_t];  // lanes hit distinct banks (129 pad), 2-way = free
            const float4 xa = *reinterpret_cast<const float4*>(&Xt[c * KC + kk][half * 8]);
            const float4 xb = *reinterpret_cast<const float4*>(&Xt[c * KC + kk][half * 8 + 4]);
            acc[0] += w * xa.x; acc[1] += w * xa.y; acc[2] += w * xa.z; acc[3] += w * xa.w;
            acc[4] += w * xb.x; acc[5] += w * xb.y; acc[6] += w * xb.z; acc[7] += w * xb.w;
        }
    }

    // ---- LayerNorm epilogue ----
    __syncthreads();
    #pragma unroll
    for (int j = 0; j < 8; ++j) u.zs[half * 8 + j][o_t] = acc[j];
    __syncthreads();
    {
        int n = t >> 4, l = t & 15;   // 16 threads per node, contiguous 16-lane groups
        float s = 0.f, ss = 0.f;
        #pragma unroll
        for (int q = 0; q < 8; ++q) {
            float v = u.zs[n][l + q * 16];
            s += v; ss += v * v;
        }
        #pragma unroll
        for (int d2 = 8; d2 >= 1; d2 >>= 1) {
            s  += __shfl_xor(s, d2, 64);
            ss += __shfl_xor(ss, d2, 64);
        }
        if (l == 0) {
            float m = s * (1.f / 128.f);
            float var = ss * (1.f / 128.f) - m * m;
            mu_s[n] = m;
            rs_s[n] = rsqrtf(var + LN_EPS);
        }
    }
    __syncthreads();
    #pragma unroll
    for (int it = 0; it < 8; ++it) {
        int i = t + 256 * it;    // 0..2047
        int n = i >> 7, o = i & 127;
        float v = (u.zs[n][o] - mu_s[n]) * rs_s[n] * gamma[o] + beta[o];
        out[(size_t)(node0 + n) * D + o] = v;
    }
}

extern "C" void kernel_launch(void* const* d_in, const int* in_sizes, int n_in,
                              void* d_out, int out_size, void* d_ws, size_t ws_size,
                              hipStream_t stream) {
    const float* h      = (const float*)d_in[0];
    const int*   ei     = (const int*)d_in[1];
    const float* deg    = (const float*)d_in[2];
    const float* Wself  = (const float*)d_in[3];
    const float* Wnb1   = (const float*)d_in[4];
    const float* Whp    = (const float*)d_in[5];
    const float* Wnb2   = (const float*)d_in[6];
    const float* bias   = (const float*)d_in[7];
    const float* logits = (const float*)d_in[8];
    const float* gamma  = (const float*)d_in[9];
    const float* beta   = (const float*)d_in[10];
    float* out = (float*)d_out;

    char* ws = (char*)d_ws;
    int* off            = (int*)(ws + WS_OFF_OFF);
    int* cnt            = (int*)(ws + WS_OFF_CNT);
    int* cur            = (int*)(ws + WS_OFF_CUR);
    int* esrc           = (int*)(ws + WS_OFF_ESRC);
    float* wc           = (float*)(ws + WS_OFF_WC);
    unsigned short* nb2 = (unsigned short*)(ws + WS_OFF_NB2);

    const int* src = ei;
    const int* dst = ei + NE;

    hipMemsetAsync(cnt, 0, NN * sizeof(int), stream);
    hipMemsetAsync(cur, 0, NN * sizeof(int), stream);

    k_weights<<<(D * D) / 256, 256, 0, stream>>>(Wself, Wnb1, Whp, Wnb2, logits, wc);
    k_count<<<NE / 256, 256, 0, stream>>>(dst, cnt);
    k_scan<<<1, 1024, 0, stream>>>(cnt, off);
    k_scatter<<<NE / 256, 256, 0, stream>>>(src, dst, off, cur, esrc);

    // hop1: nb1 (fp32) -> d_out (used as scratch; final kernel overwrites safely)
    k_hop<false><<<(NN * 64) / 256, 256, 0, stream>>>(h, (void*)out, off, esrc, deg);
    // hop2: nb2 (bf16) -> ws
    k_hop<true><<<(NN * 64) / 256, 256, 0, stream>>>(out, (void*)nb2, off, esrc, deg);

    k_gemm_ln<<<NN / TILE_N, 256, 0, stream>>>(h, out, nb2, wc, bias, gamma, beta, out);
}

// Round 2
// 644.273 us; speedup vs baseline: 1.4949x; 1.4949x over previous
//
#include <hip/hip_runtime.h>
#include <hip/hip_bf16.h>

#define NN 100000
#define NE 1600000
#define D 128
#define KTOT 640
#define LN_EPS 1e-5f
#define XPITCH 648       // ushorts per row (640 + 8 pad): 1296 B, 16B-aligned, 324 dw % 32 = 4
#define XPITCH_DW 324

// ---- workspace layout (bytes) ----
#define WS_OFF_OFF   0          // (NN+1) int
#define WS_OFF_CNT   400128     // NN int
#define WS_OFF_CUR   800256     // NN int
#define WS_OFF_ESRC  1200384    // NE int
#define WS_OFF_WCBF  7600384    // 128*640 ushort = 163840
#define WS_OFF_HHI   7764480    // NN*128 ushort = 25600000
#define WS_OFF_NB1   33364480   // NN*128 ushort = 25600000  (end 58964480)

typedef __attribute__((ext_vector_type(8))) short bf16x8;
typedef __attribute__((ext_vector_type(4))) float f32x4;

__device__ __forceinline__ unsigned short f2bf(float f) {
    unsigned u = __float_as_uint(f);
    unsigned r = (u + 0x7FFFu + ((u >> 16) & 1u)) >> 16;
    return (unsigned short)r;
}
__device__ __forceinline__ float bf2f(unsigned short b) {
    return __uint_as_float(((unsigned)b) << 16);
}

__global__ void k_prep(const float* __restrict__ h, unsigned int* __restrict__ hhi) {
    int i = blockIdx.x * blockDim.x + threadIdx.x;   // 6.4M dwords
    float2 v = reinterpret_cast<const float2*>(h)[i];
    hhi[i] = (unsigned)f2bf(v.x) | ((unsigned)f2bf(v.y) << 16);
}

__global__ void k_count(const int* __restrict__ dst, int* __restrict__ cnt) {
    int e = blockIdx.x * blockDim.x + threadIdx.x;
    if (e < NE) atomicAdd(&cnt[dst[e]], 1);
}

__global__ void k_scan(const int* __restrict__ cnt, int* __restrict__ off) {
    __shared__ int lds[1024];
    const int CH = 98;
    int t = threadIdx.x;
    int lo = t * CH;
    int hi = lo + CH; if (hi > NN) hi = NN; if (lo > NN) lo = NN;
    int s = 0;
    for (int i = lo; i < hi; ++i) s += cnt[i];
    lds[t] = s;
    __syncthreads();
    for (int ofs = 1; ofs < 1024; ofs <<= 1) {
        int v = (t >= ofs) ? lds[t - ofs] : 0;
        __syncthreads();
        lds[t] += v;
        __syncthreads();
    }
    int run = (t == 0) ? 0 : lds[t - 1];
    for (int i = lo; i < hi; ++i) { off[i] = run; run += cnt[i]; }
    if (t == 0) off[NN] = lds[1023];
}

__global__ void k_scatter(const int* __restrict__ src, const int* __restrict__ dst,
                          const int* __restrict__ off, int* __restrict__ cur,
                          int* __restrict__ esrc) {
    int e = blockIdx.x * blockDim.x + threadIdx.x;
    if (e < NE) {
        int d = dst[e];
        int p = off[d] + atomicAdd(&cur[d], 1);
        esrc[p] = src[e];
    }
}

// combined weights -> bf16, [o][640]: segs {Wc1, Wc1, Wc2, Wc3hi-seg, Wc3lo-seg}
__global__ void k_weights(const float* __restrict__ Ws, const float* __restrict__ W1,
                          const float* __restrict__ Whp, const float* __restrict__ W2,
                          const float* __restrict__ logits, unsigned short* __restrict__ wcbf) {
    int idx = blockIdx.x * blockDim.x + threadIdx.x;
    if (idx >= D * D) return;
    int o = idx >> 7, k = idx & 127;
    float s0 = 2.f / (1.f + __expf(-logits[0]));
    float s1 = 2.f / (1.f + __expf(-logits[1]));
    float s2 = 2.f / (1.f + __expf(-logits[2]));
    float s3 = 2.f / (1.f + __expf(-logits[3]));
    unsigned short b1 = f2bf(s0 * Ws[idx] + s2 * Whp[idx]);
    unsigned short b2 = f2bf(s1 * W1[idx] - s2 * Whp[idx]);
    unsigned short b3 = f2bf(s3 * W2[idx]);
    size_t base = (size_t)o * KTOT + k;
    wcbf[base]       = b1;   // h_hi
    wcbf[base + 128] = b1;   // h_lo
    wcbf[base + 256] = b2;   // nb1
    wcbf[base + 384] = b3;   // nb2_hi
    wcbf[base + 512] = b3;   // nb2_lo
}

// one wave per node; lane owns 2 dims packed in one dword (bf16 pair).
// OUT_F32: write float2 (nb2 -> d_out). else: write bf16 pair dword (nb1_hi).
template <bool OUT_F32>
__global__ void k_hop(const unsigned int* __restrict__ in, void* __restrict__ outv,
                      const int* __restrict__ off, const int* __restrict__ esrc,
                      const float* __restrict__ deg) {
    int w = (blockIdx.x * blockDim.x + threadIdx.x) >> 6;
    int lane = threadIdx.x & 63;
    int beg = __builtin_amdgcn_readfirstlane(off[w]);
    int end = __builtin_amdgcn_readfirstlane(off[w + 1]);
    float ax = 0.f, ay = 0.f;
    int j = beg;
    for (; j + 3 < end; j += 4) {
        int s0 = __builtin_amdgcn_readfirstlane(esrc[j]);
        int s1 = __builtin_amdgcn_readfirstlane(esrc[j + 1]);
        int s2 = __builtin_amdgcn_readfirstlane(esrc[j + 2]);
        int s3 = __builtin_amdgcn_readfirstlane(esrc[j + 3]);
        unsigned u0 = in[(size_t)s0 * 64 + lane];
        unsigned u1 = in[(size_t)s1 * 64 + lane];
        unsigned u2 = in[(size_t)s2 * 64 + lane];
        unsigned u3 = in[(size_t)s3 * 64 + lane];
        ax += __uint_as_float(u0 << 16);            ay += __uint_as_float(u0 & 0xffff0000u);
        ax += __uint_as_float(u1 << 16);            ay += __uint_as_float(u1 & 0xffff0000u);
        ax += __uint_as_float(u2 << 16);            ay += __uint_as_float(u2 & 0xffff0000u);
        ax += __uint_as_float(u3 << 16);            ay += __uint_as_float(u3 & 0xffff0000u);
    }
    for (; j < end; ++j) {
        int s0 = __builtin_amdgcn_readfirstlane(esrc[j]);
        unsigned u0 = in[(size_t)s0 * 64 + lane];
        ax += __uint_as_float(u0 << 16);            ay += __uint_as_float(u0 & 0xffff0000u);
    }
    float inv = 1.0f / deg[w];
    ax *= inv; ay *= inv;
    if (OUT_F32) {
        float2 p; p.x = ax; p.y = ay;
        reinterpret_cast<float2*>(outv)[(size_t)w * 64 + lane] = p;
    } else {
        reinterpret_cast<unsigned int*>(outv)[(size_t)w * 64 + lane] =
            (unsigned)f2bf(ax) | ((unsigned)f2bf(ay) << 16);
    }
}

// MFMA GEMM (M=32/block, N=128, K=640) + fused LayerNorm.
// X = [h_hi | h_lo | nb1 | nb2_hi | nb2_lo] bf16; B-frags cached in regs per 320-K chunk.
__global__ __launch_bounds__(256) void k_gemm_ln(
    const unsigned int* __restrict__ hhi, const float* __restrict__ hf,
    const unsigned int* __restrict__ nb1u, const float* __restrict__ nb2f,
    const unsigned short* __restrict__ wcbf, const float* __restrict__ bias,
    const float* __restrict__ gamma, const float* __restrict__ beta,
    float* __restrict__ out) {
    __shared__ __align__(16) unsigned short Xs[32 * XPITCH];   // 41472 B; aliased by zs in epilogue
    __shared__ float mu_s[32], rs_s[32];
    unsigned int* Xs_u = reinterpret_cast<unsigned int*>(Xs);
    float* zs = reinterpret_cast<float*>(Xs);                  // [32][132]

    const int t = threadIdx.x;
    const int node0 = blockIdx.x * 32;

    // ---- staging: 32 rows x 64 dwords per segment ----
    #pragma unroll
    for (int it = 0; it < 8; ++it) {
        int i = t + 256 * it;
        int row = i >> 6, d = i & 63;
        size_t g = (size_t)(node0 + row) * 64 + d;
        int lb = row * XPITCH_DW + d;
        unsigned hh = hhi[g];
        Xs_u[lb] = hh;                                          // seg0: h_hi
        float2 hv = reinterpret_cast<const float2*>(hf)[g];
        unsigned lo = (unsigned)f2bf(hv.x - bf2f((unsigned short)(hh & 0xffffu)))
                    | ((unsigned)f2bf(hv.y - bf2f((unsigned short)(hh >> 16))) << 16);
        Xs_u[lb + 64] = lo;                                     // seg1: h_lo
        Xs_u[lb + 128] = nb1u[g];                               // seg2: nb1
        float2 nv = reinterpret_cast<const float2*>(nb2f)[g];
        unsigned short n0 = f2bf(nv.x), n1 = f2bf(nv.y);
        Xs_u[lb + 192] = (unsigned)n0 | ((unsigned)n1 << 16);   // seg3: nb2_hi
        Xs_u[lb + 256] = (unsigned)f2bf(nv.x - bf2f(n0))
                       | ((unsigned)f2bf(nv.y - bf2f(n1)) << 16); // seg4: nb2_lo
    }
    __syncthreads();

    const int wv = t >> 6, lane = t & 63;
    const int lm = lane & 15, quad = lane >> 4;

    f32x4 acc[2][2] = {{{0.f, 0.f, 0.f, 0.f}, {0.f, 0.f, 0.f, 0.f}},
                       {{0.f, 0.f, 0.f, 0.f}, {0.f, 0.f, 0.f, 0.f}}};

    for (int c = 0; c < 2; ++c) {
        bf16x8 bfr[2][10];
        #pragma unroll
        for (int nt = 0; nt < 2; ++nt) {
            #pragma unroll
            for (int s = 0; s < 10; ++s) {
                int o = wv * 32 + nt * 16 + lm;
                int k = c * 320 + s * 32 + quad * 8;
                bfr[nt][s] = *reinterpret_cast<const bf16x8*>(wcbf + (size_t)o * KTOT + k);
            }
        }
        #pragma unroll
        for (int s = 0; s < 10; ++s) {
            int koff = c * 320 + s * 32 + quad * 8;
            bf16x8 a0 = *reinterpret_cast<const bf16x8*>(&Xs[(0 * 16 + lm) * XPITCH + koff]);
            bf16x8 a1 = *reinterpret_cast<const bf16x8*>(&Xs[(1 * 16 + lm) * XPITCH + koff]);
            #pragma unroll
            for (int nt = 0; nt < 2; ++nt) {
                acc[0][nt] = __builtin_amdgcn_mfma_f32_16x16x32_bf16(a0, bfr[nt][s], acc[0][nt], 0, 0, 0);
                acc[1][nt] = __builtin_amdgcn_mfma_f32_16x16x32_bf16(a1, bfr[nt][s], acc[1][nt], 0, 0, 0);
            }
        }
    }
    __syncthreads();   // all waves done reading Xs before zs overwrite

    // ---- z -> LDS (add bias); C layout: col = lane&15, row = quad*4 + reg ----
    #pragma unroll
    for (int nt = 0; nt < 2; ++nt) {
        int o = wv * 32 + nt * 16 + lm;
        float bv = bias[o];
        #pragma unroll
        for (int mt = 0; mt < 2; ++mt) {
            #pragma unroll
            for (int r = 0; r < 4; ++r) {
                int m = mt * 16 + quad * 4 + r;
                zs[m * 132 + o] = acc[mt][nt][r] + bv;
            }
        }
    }
    __syncthreads();

    {   // LN stats: 8 threads per node
        int n = t >> 3, l = t & 7;
        float s = 0.f, ss = 0.f;
        #pragma unroll
        for (int q = 0; q < 16; ++q) {
            float v = zs[n * 132 + l + 8 * q];
            s += v; ss += v * v;
        }
        s += __shfl_xor(s, 1);  ss += __shfl_xor(ss, 1);
        s += __shfl_xor(s, 2);  ss += __shfl_xor(ss, 2);
        s += __shfl_xor(s, 4);  ss += __shfl_xor(ss, 4);
        if (l == 0) {
            float m = s * (1.f / 128.f);
            float var = ss * (1.f / 128.f) - m * m;
            mu_s[n] = m;
            rs_s[n] = rsqrtf(var + LN_EPS);
        }
    }
    __syncthreads();

    #pragma unroll
    for (int it = 0; it < 16; ++it) {
        int i = t + 256 * it;
        int n = i >> 7, o = i & 127;
        float v = (zs[n * 132 + o] - mu_s[n]) * rs_s[n] * gamma[o] + beta[o];
        out[(size_t)(node0 + n) * D + o] = v;
    }
}

extern "C" void kernel_launch(void* const* d_in, const int* in_sizes, int n_in,
                              void* d_out, int out_size, void* d_ws, size_t ws_size,
                              hipStream_t stream) {
    const float* h      = (const float*)d_in[0];
    const int*   ei     = (const int*)d_in[1];
    const float* deg    = (const float*)d_in[2];
    const float* Wself  = (const float*)d_in[3];
    const float* Wnb1   = (const float*)d_in[4];
    const float* Whp    = (const float*)d_in[5];
    const float* Wnb2   = (const float*)d_in[6];
    const float* bias   = (const float*)d_in[7];
    const float* logits = (const float*)d_in[8];
    const float* gamma  = (const float*)d_in[9];
    const float* beta   = (const float*)d_in[10];
    float* out = (float*)d_out;

    char* ws = (char*)d_ws;
    int* off                 = (int*)(ws + WS_OFF_OFF);
    int* cnt                 = (int*)(ws + WS_OFF_CNT);
    int* cur                 = (int*)(ws + WS_OFF_CUR);
    int* esrc                = (int*)(ws + WS_OFF_ESRC);
    unsigned short* wcbf     = (unsigned short*)(ws + WS_OFF_WCBF);
    unsigned int* hhi        = (unsigned int*)(ws + WS_OFF_HHI);
    unsigned int* nb1u       = (unsigned int*)(ws + WS_OFF_NB1);

    const int* src = ei;
    const int* dst = ei + NE;

    hipMemsetAsync(cnt, 0, NN * sizeof(int), stream);
    hipMemsetAsync(cur, 0, NN * sizeof(int), stream);

    k_prep<<<25000, 256, 0, stream>>>(h, hhi);
    k_weights<<<64, 256, 0, stream>>>(Wself, Wnb1, Whp, Wnb2, logits, wcbf);
    k_count<<<NE / 256, 256, 0, stream>>>(dst, cnt);
    k_scan<<<1, 1024, 0, stream>>>(cnt, off);
    k_scatter<<<NE / 256, 256, 0, stream>>>(src, dst, off, cur, esrc);

    // hop1: gather h_hi (bf16) -> nb1_hi (bf16, ws)
    k_hop<false><<<(NN * 64) / 256, 256, 0, stream>>>(hhi, (void*)nb1u, off, esrc, deg);
    // hop2: gather nb1_hi (bf16) -> nb2 (fp32, d_out scratch; gemm reads own rows then overwrites)
    k_hop<true><<<(NN * 64) / 256, 256, 0, stream>>>(nb1u, (void*)out, off, esrc, deg);

    k_gemm_ln<<<NN / 32, 256, 0, stream>>>(hhi, h, nb1u, out, wcbf, bias, gamma, beta, out);
}

// Round 3
// 480.997 us; speedup vs baseline: 2.0023x; 1.3395x over previous
//
#include <hip/hip_runtime.h>
#include <hip/hip_bf16.h>

#define NN 100000
#define NE 1600000
#define D 128
#define KTOT 640
#define LN_EPS 1e-5f
#define XPITCH 648       // ushorts per row (640 + 8 pad): 1296 B, 16B-aligned, 324 dw % 32 = 4
#define XPITCH_DW 324

#define SCAN_CHUNK 2048
#define NSB 49           // ceil(NN / SCAN_CHUNK)
#define CNT_PAD 100352   // NSB*SCAN_CHUNK, zero-padded so int4 loads need no guard

// ---- workspace layout (bytes) ----
#define WS_OFF_OFF   0          // 100352 ints (only NN+1 meaningful; pad absorbs tail writes)
#define WS_OFF_CNT   401408     // 100352 ints (zeroed each launch)
#define WS_OFF_CUR   802816     // NN int
#define WS_OFF_ESRC  1204224    // NE int
#define WS_OFF_BSUM  7604224    // NSB+1 ints
#define WS_OFF_WCBF  7604480    // 128*640 ushort = 163840
#define WS_OFF_HHI   7768320    // NN*128 ushort = 25600000
#define WS_OFF_NB1   33368320   // NN*128 ushort = 25600000  (end 58968320)

typedef __attribute__((ext_vector_type(8))) short bf16x8;
typedef __attribute__((ext_vector_type(4))) float f32x4;

__device__ __forceinline__ unsigned short f2bf(float f) {
    unsigned u = __float_as_uint(f);
    unsigned r = (u + 0x7FFFu + ((u >> 16) & 1u)) >> 16;
    return (unsigned short)r;
}
__device__ __forceinline__ float bf2f(unsigned short b) {
    return __uint_as_float(((unsigned)b) << 16);
}

__global__ void k_prep(const float* __restrict__ h, unsigned int* __restrict__ hhi) {
    int i = blockIdx.x * blockDim.x + threadIdx.x;   // 6.4M dwords
    float2 v = reinterpret_cast<const float2*>(h)[i];
    hhi[i] = (unsigned)f2bf(v.x) | ((unsigned)f2bf(v.y) << 16);
}

__global__ void k_count(const int* __restrict__ dst, int* __restrict__ cnt) {
    int e = blockIdx.x * blockDim.x + threadIdx.x;
    if (e < NE) atomicAdd(&cnt[dst[e]], 1);
}

// pass 1: per-block (2048 elems) local exclusive scan -> off, block total -> bsum
__global__ __launch_bounds__(256) void k_scan1(const int* __restrict__ cnt,
                                               int* __restrict__ off,
                                               int* __restrict__ bsum) {
    __shared__ int lds[256];
    int t = threadIdx.x, b = blockIdx.x;
    int base = b * SCAN_CHUNK + t * 8;
    int4 a0 = reinterpret_cast<const int4*>(cnt)[base >> 2];
    int4 a1 = reinterpret_cast<const int4*>(cnt)[(base >> 2) + 1];
    int v[8] = {a0.x, a0.y, a0.z, a0.w, a1.x, a1.y, a1.z, a1.w};
    int s = 0;
    #pragma unroll
    for (int j = 0; j < 8; ++j) s += v[j];
    lds[t] = s;
    __syncthreads();
    for (int ofs = 1; ofs < 256; ofs <<= 1) {
        int x = (t >= ofs) ? lds[t - ofs] : 0;
        __syncthreads();
        lds[t] += x;
        __syncthreads();
    }
    int excl = (t == 0) ? 0 : lds[t - 1];
    #pragma unroll
    for (int j = 0; j < 8; ++j) { off[base + j] = excl; excl += v[j]; }  // pad absorbs i>=NN
    if (t == 255) bsum[b] = lds[255];
}

// pass 2: one wave scans the 49 block sums (exclusive) + grand total
__global__ void k_scan2(int* __restrict__ bsum) {
    int t = threadIdx.x;
    int v = (t < NSB) ? bsum[t] : 0;
    #pragma unroll
    for (int ofs = 1; ofs < 64; ofs <<= 1) {
        int x = __shfl_up(v, ofs, 64);
        if (t >= ofs) v += x;
    }
    int excl = __shfl_up(v, 1, 64);
    if (t == 0) excl = 0;
    if (t < NSB) bsum[t] = excl;
    if (t == NSB - 1) bsum[NSB] = v;
}

// pass 3: add block offsets, write off[NN]
__global__ void k_scan3(int* __restrict__ off, const int* __restrict__ bsum) {
    int i = blockIdx.x * blockDim.x + threadIdx.x;
    if (i < NN) off[i] += bsum[i >> 11];
    if (i == 0) off[NN] = bsum[NSB];
}

__global__ void k_scatter(const int* __restrict__ src, const int* __restrict__ dst,
                          const int* __restrict__ off, int* __restrict__ cur,
                          int* __restrict__ esrc) {
    int e = blockIdx.x * blockDim.x + threadIdx.x;
    if (e < NE) {
        int d = dst[e];
        int p = off[d] + atomicAdd(&cur[d], 1);
        esrc[p] = src[e];
    }
}

// combined weights -> bf16, [o][640]: segs {Wc1, Wc1, Wc2, Wc3, Wc3}
__global__ void k_weights(const float* __restrict__ Ws, const float* __restrict__ W1,
                          const float* __restrict__ Whp, const float* __restrict__ W2,
                          const float* __restrict__ logits, unsigned short* __restrict__ wcbf) {
    int idx = blockIdx.x * blockDim.x + threadIdx.x;
    if (idx >= D * D) return;
    int o = idx >> 7, k = idx & 127;
    float s0 = 2.f / (1.f + __expf(-logits[0]));
    float s1 = 2.f / (1.f + __expf(-logits[1]));
    float s2 = 2.f / (1.f + __expf(-logits[2]));
    float s3 = 2.f / (1.f + __expf(-logits[3]));
    unsigned short b1 = f2bf(s0 * Ws[idx] + s2 * Whp[idx]);
    unsigned short b2 = f2bf(s1 * W1[idx] - s2 * Whp[idx]);
    unsigned short b3 = f2bf(s3 * W2[idx]);
    size_t base = (size_t)o * KTOT + k;
    wcbf[base]       = b1;   // h_hi
    wcbf[base + 128] = b1;   // h_lo
    wcbf[base + 256] = b2;   // nb1
    wcbf[base + 384] = b3;   // nb2_hi
    wcbf[base + 512] = b3;   // nb2_lo
}

// one wave per node; lane owns 2 dims packed in one dword (bf16 pair).
// OUT_F32: write float2 (nb2 -> d_out). else: write bf16 pair dword (nb1_hi).
template <bool OUT_F32>
__global__ void k_hop(const unsigned int* __restrict__ in, void* __restrict__ outv,
                      const int* __restrict__ off, const int* __restrict__ esrc,
                      const float* __restrict__ deg) {
    int w = (blockIdx.x * blockDim.x + threadIdx.x) >> 6;
    int lane = threadIdx.x & 63;
    int beg = __builtin_amdgcn_readfirstlane(off[w]);
    int end = __builtin_amdgcn_readfirstlane(off[w + 1]);
    float ax = 0.f, ay = 0.f;
    int j = beg;
    for (; j + 3 < end; j += 4) {
        int s0 = __builtin_amdgcn_readfirstlane(esrc[j]);
        int s1 = __builtin_amdgcn_readfirstlane(esrc[j + 1]);
        int s2 = __builtin_amdgcn_readfirstlane(esrc[j + 2]);
        int s3 = __builtin_amdgcn_readfirstlane(esrc[j + 3]);
        unsigned u0 = in[(size_t)s0 * 64 + lane];
        unsigned u1 = in[(size_t)s1 * 64 + lane];
        unsigned u2 = in[(size_t)s2 * 64 + lane];
        unsigned u3 = in[(size_t)s3 * 64 + lane];
        ax += __uint_as_float(u0 << 16);            ay += __uint_as_float(u0 & 0xffff0000u);
        ax += __uint_as_float(u1 << 16);            ay += __uint_as_float(u1 & 0xffff0000u);
        ax += __uint_as_float(u2 << 16);            ay += __uint_as_float(u2 & 0xffff0000u);
        ax += __uint_as_float(u3 << 16);            ay += __uint_as_float(u3 & 0xffff0000u);
    }
    for (; j < end; ++j) {
        int s0 = __builtin_amdgcn_readfirstlane(esrc[j]);
        unsigned u0 = in[(size_t)s0 * 64 + lane];
        ax += __uint_as_float(u0 << 16);            ay += __uint_as_float(u0 & 0xffff0000u);
    }
    float inv = 1.0f / deg[w];
    ax *= inv; ay *= inv;
    if (OUT_F32) {
        float2 p; p.x = ax; p.y = ay;
        reinterpret_cast<float2*>(outv)[(size_t)w * 64 + lane] = p;
    } else {
        reinterpret_cast<unsigned int*>(outv)[(size_t)w * 64 + lane] =
            (unsigned)f2bf(ax) | ((unsigned)f2bf(ay) << 16);
    }
}

// MFMA GEMM (M=32/block, N=128, K=640) + fused LayerNorm.
// X = [h_hi | h_lo | nb1 | nb2_hi | nb2_lo] bf16; B-frags cached in regs per 320-K chunk.
__global__ __launch_bounds__(256) void k_gemm_ln(
    const unsigned int* __restrict__ hhi, const float* __restrict__ hf,
    const unsigned int* __restrict__ nb1u, const float* __restrict__ nb2f,
    const unsigned short* __restrict__ wcbf, const float* __restrict__ bias,
    const float* __restrict__ gamma, const float* __restrict__ beta,
    float* __restrict__ out) {
    __shared__ __align__(16) unsigned short Xs[32 * XPITCH];   // 41472 B; aliased by zs in epilogue
    __shared__ float mu_s[32], rs_s[32];
    unsigned int* Xs_u = reinterpret_cast<unsigned int*>(Xs);
    float* zs = reinterpret_cast<float*>(Xs);                  // [32][132]

    const int t = threadIdx.x;
    const int node0 = blockIdx.x * 32;

    // ---- staging: 32 rows x 64 dwords per segment ----
    #pragma unroll
    for (int it = 0; it < 8; ++it) {
        int i = t + 256 * it;
        int row = i >> 6, d = i & 63;
        size_t g = (size_t)(node0 + row) * 64 + d;
        int lb = row * XPITCH_DW + d;
        unsigned hh = hhi[g];
        Xs_u[lb] = hh;                                          // seg0: h_hi
        float2 hv = reinterpret_cast<const float2*>(hf)[g];
        unsigned lo = (unsigned)f2bf(hv.x - bf2f((unsigned short)(hh & 0xffffu)))
                    | ((unsigned)f2bf(hv.y - bf2f((unsigned short)(hh >> 16))) << 16);
        Xs_u[lb + 64] = lo;                                     // seg1: h_lo
        Xs_u[lb + 128] = nb1u[g];                               // seg2: nb1
        float2 nv = reinterpret_cast<const float2*>(nb2f)[g];
        unsigned short n0 = f2bf(nv.x), n1 = f2bf(nv.y);
        Xs_u[lb + 192] = (unsigned)n0 | ((unsigned)n1 << 16);   // seg3: nb2_hi
        Xs_u[lb + 256] = (unsigned)f2bf(nv.x - bf2f(n0))
                       | ((unsigned)f2bf(nv.y - bf2f(n1)) << 16); // seg4: nb2_lo
    }
    __syncthreads();

    const int wv = t >> 6, lane = t & 63;
    const int lm = lane & 15, quad = lane >> 4;

    f32x4 acc[2][2] = {{{0.f, 0.f, 0.f, 0.f}, {0.f, 0.f, 0.f, 0.f}},
                       {{0.f, 0.f, 0.f, 0.f}, {0.f, 0.f, 0.f, 0.f}}};

    for (int c = 0; c < 2; ++c) {
        bf16x8 bfr[2][10];
        #pragma unroll
        for (int nt = 0; nt < 2; ++nt) {
            #pragma unroll
            for (int s = 0; s < 10; ++s) {
                int o = wv * 32 + nt * 16 + lm;
                int k = c * 320 + s * 32 + quad * 8;
                bfr[nt][s] = *reinterpret_cast<const bf16x8*>(wcbf + (size_t)o * KTOT + k);
            }
        }
        #pragma unroll
        for (int s = 0; s < 10; ++s) {
            int koff = c * 320 + s * 32 + quad * 8;
            bf16x8 a0 = *reinterpret_cast<const bf16x8*>(&Xs[(0 * 16 + lm) * XPITCH + koff]);
            bf16x8 a1 = *reinterpret_cast<const bf16x8*>(&Xs[(1 * 16 + lm) * XPITCH + koff]);
            #pragma unroll
            for (int nt = 0; nt < 2; ++nt) {
                acc[0][nt] = __builtin_amdgcn_mfma_f32_16x16x32_bf16(a0, bfr[nt][s], acc[0][nt], 0, 0, 0);
                acc[1][nt] = __builtin_amdgcn_mfma_f32_16x16x32_bf16(a1, bfr[nt][s], acc[1][nt], 0, 0, 0);
            }
        }
    }
    __syncthreads();   // all waves done reading Xs before zs overwrite

    // ---- z -> LDS (add bias); C layout: col = lane&15, row = quad*4 + reg ----
    #pragma unroll
    for (int nt = 0; nt < 2; ++nt) {
        int o = wv * 32 + nt * 16 + lm;
        float bv = bias[o];
        #pragma unroll
        for (int mt = 0; mt < 2; ++mt) {
            #pragma unroll
            for (int r = 0; r < 4; ++r) {
                int m = mt * 16 + quad * 4 + r;
                zs[m * 132 + o] = acc[mt][nt][r] + bv;
            }
        }
    }
    __syncthreads();

    {   // LN stats: 8 threads per node
        int n = t >> 3, l = t & 7;
        float s = 0.f, ss = 0.f;
        #pragma unroll
        for (int q = 0; q < 16; ++q) {
            float v = zs[n * 132 + l + 8 * q];
            s += v; ss += v * v;
        }
        s += __shfl_xor(s, 1);  ss += __shfl_xor(ss, 1);
        s += __shfl_xor(s, 2);  ss += __shfl_xor(ss, 2);
        s += __shfl_xor(s, 4);  ss += __shfl_xor(ss, 4);
        if (l == 0) {
            float m = s * (1.f / 128.f);
            float var = ss * (1.f / 128.f) - m * m;
            mu_s[n] = m;
            rs_s[n] = rsqrtf(var + LN_EPS);
        }
    }
    __syncthreads();

    #pragma unroll
    for (int it = 0; it < 16; ++it) {
        int i = t + 256 * it;
        int n = i >> 7, o = i & 127;
        float v = (zs[n * 132 + o] - mu_s[n]) * rs_s[n] * gamma[o] + beta[o];
        out[(size_t)(node0 + n) * D + o] = v;
    }
}

extern "C" void kernel_launch(void* const* d_in, const int* in_sizes, int n_in,
                              void* d_out, int out_size, void* d_ws, size_t ws_size,
                              hipStream_t stream) {
    const float* h      = (const float*)d_in[0];
    const int*   ei     = (const int*)d_in[1];
    const float* deg    = (const float*)d_in[2];
    const float* Wself  = (const float*)d_in[3];
    const float* Wnb1   = (const float*)d_in[4];
    const float* Whp    = (const float*)d_in[5];
    const float* Wnb2   = (const float*)d_in[6];
    const float* bias   = (const float*)d_in[7];
    const float* logits = (const float*)d_in[8];
    const float* gamma  = (const float*)d_in[9];
    const float* beta   = (const float*)d_in[10];
    float* out = (float*)d_out;

    char* ws = (char*)d_ws;
    int* off                 = (int*)(ws + WS_OFF_OFF);
    int* cnt                 = (int*)(ws + WS_OFF_CNT);
    int* cur                 = (int*)(ws + WS_OFF_CUR);
    int* esrc                = (int*)(ws + WS_OFF_ESRC);
    int* bsum                = (int*)(ws + WS_OFF_BSUM);
    unsigned short* wcbf     = (unsigned short*)(ws + WS_OFF_WCBF);
    unsigned int* hhi        = (unsigned int*)(ws + WS_OFF_HHI);
    unsigned int* nb1u       = (unsigned int*)(ws + WS_OFF_NB1);

    const int* src = ei;
    const int* dst = ei + NE;

    hipMemsetAsync(cnt, 0, CNT_PAD * sizeof(int), stream);
    hipMemsetAsync(cur, 0, NN * sizeof(int), stream);

    k_prep<<<25000, 256, 0, stream>>>(h, hhi);
    k_weights<<<64, 256, 0, stream>>>(Wself, Wnb1, Whp, Wnb2, logits, wcbf);
    k_count<<<NE / 256, 256, 0, stream>>>(dst, cnt);
    k_scan1<<<NSB, 256, 0, stream>>>(cnt, off, bsum);
    k_scan2<<<1, 64, 0, stream>>>(bsum);
    k_scan3<<<(NN + 255) / 256, 256, 0, stream>>>(off, bsum);
    k_scatter<<<NE / 256, 256, 0, stream>>>(src, dst, off, cur, esrc);

    // hop1: gather h_hi (bf16) -> nb1_hi (bf16, ws)
    k_hop<false><<<(NN * 64) / 256, 256, 0, stream>>>(hhi, (void*)nb1u, off, esrc, deg);
    // hop2: gather nb1_hi (bf16) -> nb2 (fp32, d_out scratch; gemm reads own rows then overwrites)
    k_hop<true><<<(NN * 64) / 256, 256, 0, stream>>>(nb1u, (void*)out, off, esrc, deg);

    k_gemm_ln<<<NN / 32, 256, 0, stream>>>(hhi, h, nb1u, out, wcbf, bias, gamma, beta, out);
}

// Round 4
// 417.677 us; speedup vs baseline: 2.3059x; 1.1516x over previous
//
#include <hip/hip_runtime.h>
#include <hip/hip_bf16.h>

#define NN 100000
#define NE 1600000
#define D 128
#define KTOT 640
#define LN_EPS 1e-5f
#define XPITCH 648       // ushorts per row (640 + 8 pad): 1296 B, 16B-aligned, 324 dw % 32 = 4
#define XPITCH_DW 324

#define SCAN_CHUNK 2048
#define NSB 49           // ceil(NN / SCAN_CHUNK)

#define NBK 98           // dst buckets (dst >> 10), 1024 nodes each
#define BCAP 20480       // slots per bucket (avg fill 16.3K, sigma ~126)

// ---- workspace layout (bytes) ----
// off  : 100352 int   @ 0        (only NN+1 meaningful; pad absorbs tail writes)
// cur  : 100352 int   @ 401408   (memset to 0; post-scatter = per-node edge count)
// bsum : 64 int       @ 802816
// gcur : 128 int      @ 803072   (memset to 0)
// wcbf : 128*640 u16  @ 803584   (163840)
// esrc : 1.7M int     @ 967680   (6800000; sum(max(deg,1)) <= NE+NN)
// REGION_A @ 7768064  : gbuf 98*20480*8 = 16056320, then reused as hhi (25600000)
// nb1  : NN*128 u16   @ 33368064 (25600000, end 58968064)
#define WS_OFF_OFF   0
#define WS_OFF_CUR   401408
#define WS_OFF_BSUM  802816
#define WS_OFF_GCUR  803072
#define WS_OFF_WCBF  803584
#define WS_OFF_ESRC  967680
#define WS_OFF_GBUF  7768064
#define WS_OFF_HHI   7768064
#define WS_OFF_NB1   33368064

typedef __attribute__((ext_vector_type(8))) short bf16x8;
typedef __attribute__((ext_vector_type(4))) float f32x4;

__device__ __forceinline__ unsigned short f2bf(float f) {
    unsigned u = __float_as_uint(f);
    unsigned r = (u + 0x7FFFu + ((u >> 16) & 1u)) >> 16;
    return (unsigned short)r;
}
__device__ __forceinline__ float bf2f(unsigned short b) {
    return __uint_as_float(((unsigned)b) << 16);
}

__global__ void k_prep(const float* __restrict__ h, unsigned int* __restrict__ hhi) {
    int i = blockIdx.x * blockDim.x + threadIdx.x;   // 6.4M dwords
    float2 v = reinterpret_cast<const float2*>(h)[i];
    hhi[i] = (unsigned)f2bf(v.x) | ((unsigned)f2bf(v.y) << 16);
}

// pass 1: scan int(deg) per 2048-chunk -> off (local excl), block total -> bsum
__global__ __launch_bounds__(256) void k_scan1(const float* __restrict__ deg,
                                               int* __restrict__ off,
                                               int* __restrict__ bsum) {
    __shared__ int lds[256];
    int t = threadIdx.x, b = blockIdx.x;
    int base = b * SCAN_CHUNK + t * 8;
    int v[8];
    if (base < NN) {   // NN % 8 == 0, so base < NN implies base+8 <= NN
        float4 a0 = reinterpret_cast<const float4*>(deg + base)[0];
        float4 a1 = reinterpret_cast<const float4*>(deg + base)[1];
        v[0] = __float2int_rn(a0.x); v[1] = __float2int_rn(a0.y);
        v[2] = __float2int_rn(a0.z); v[3] = __float2int_rn(a0.w);
        v[4] = __float2int_rn(a1.x); v[5] = __float2int_rn(a1.y);
        v[6] = __float2int_rn(a1.z); v[7] = __float2int_rn(a1.w);
    } else {
        #pragma unroll
        for (int j = 0; j < 8; ++j) v[j] = 0;
    }
    int s = 0;
    #pragma unroll
    for (int j = 0; j < 8; ++j) s += v[j];
    lds[t] = s;
    __syncthreads();
    for (int ofs = 1; ofs < 256; ofs <<= 1) {
        int x = (t >= ofs) ? lds[t - ofs] : 0;
        __syncthreads();
        lds[t] += x;
        __syncthreads();
    }
    int excl = (t == 0) ? 0 : lds[t - 1];
    #pragma unroll
    for (int j = 0; j < 8; ++j) { off[base + j] = excl; excl += v[j]; }  // pad absorbs i>=NN
    if (t == 255) bsum[b] = lds[255];
}

// pass 2: one wave scans the 49 block sums (exclusive) + grand total
__global__ void k_scan2(int* __restrict__ bsum) {
    int t = threadIdx.x;
    int v = (t < NSB) ? bsum[t] : 0;
    #pragma unroll
    for (int ofs = 1; ofs < 64; ofs <<= 1) {
        int x = __shfl_up(v, ofs, 64);
        if (t >= ofs) v += x;
    }
    int excl = __shfl_up(v, 1, 64);
    if (t == 0) excl = 0;
    if (t < NSB) bsum[t] = excl;
    if (t == NSB - 1) bsum[NSB] = v;
}

// pass 3: add block offsets
__global__ void k_scan3(int* __restrict__ off, const int* __restrict__ bsum) {
    int i = blockIdx.x * blockDim.x + threadIdx.x;
    if (i < NN) off[i] += bsum[i >> 11];
    if (i == 0) off[NN] = bsum[NSB];
}

// binning pass A: edges -> 98 dst-range buckets, LDS-aggregated ranks
__global__ __launch_bounds__(256) void k_bin(const int* __restrict__ src,
                                             const int* __restrict__ dst,
                                             int* __restrict__ gcur,
                                             int2* __restrict__ gbuf) {
    __shared__ int bcnt[NBK];
    __shared__ int bbase[NBK];
    int t = threadIdx.x;
    if (t < NBK) bcnt[t] = 0;
    __syncthreads();
    int e0 = blockIdx.x * 2048;
    int s[8], d[8], r[8];
    #pragma unroll
    for (int it = 0; it < 8; ++it) {
        int e = e0 + it * 256 + t;
        bool ok = e < NE;
        s[it] = ok ? src[e] : 0;
        d[it] = ok ? dst[e] : -1;
        r[it] = ok ? atomicAdd(&bcnt[d[it] >> 10], 1) : 0;
    }
    __syncthreads();
    if (t < NBK) bbase[t] = atomicAdd(&gcur[t], bcnt[t]);
    __syncthreads();
    #pragma unroll
    for (int it = 0; it < 8; ++it) {
        if (d[it] >= 0) {
            int bk = d[it] >> 10;
            gbuf[(size_t)bk * BCAP + bbase[bk] + r[it]] = make_int2(s[it], d[it]);
        }
    }
}

// scatter pass B: one block per bucket; esrc/cur writes stay in a ~70KB L2 window
__global__ __launch_bounds__(1024) void k_scatter2(const int2* __restrict__ gbuf,
                                                   const int* __restrict__ gcur,
                                                   const int* __restrict__ off,
                                                   int* __restrict__ cur,
                                                   int* __restrict__ esrc) {
    int b = blockIdx.x;
    int nb = gcur[b];
    const int2* bb = gbuf + (size_t)b * BCAP;
    for (int i = threadIdx.x; i < nb; i += 1024) {
        int2 e = bb[i];
        int p = off[e.y] + atomicAdd(&cur[e.y], 1);
        esrc[p] = e.x;
    }
}

// combined weights -> bf16, [o][640]: segs {Wc1, Wc1, Wc2, Wc3, Wc3}
__global__ void k_weights(const float* __restrict__ Ws, const float* __restrict__ W1,
                          const float* __restrict__ Whp, const float* __restrict__ W2,
                          const float* __restrict__ logits, unsigned short* __restrict__ wcbf) {
    int idx = blockIdx.x * blockDim.x + threadIdx.x;
    if (idx >= D * D) return;
    int o = idx >> 7, k = idx & 127;
    float s0 = 2.f / (1.f + __expf(-logits[0]));
    float s1 = 2.f / (1.f + __expf(-logits[1]));
    float s2 = 2.f / (1.f + __expf(-logits[2]));
    float s3 = 2.f / (1.f + __expf(-logits[3]));
    unsigned short b1 = f2bf(s0 * Ws[idx] + s2 * Whp[idx]);
    unsigned short b2 = f2bf(s1 * W1[idx] - s2 * Whp[idx]);
    unsigned short b3 = f2bf(s3 * W2[idx]);
    size_t base = (size_t)o * KTOT + k;
    wcbf[base]       = b1;   // h_hi
    wcbf[base + 128] = b1;   // h_lo
    wcbf[base + 256] = b2;   // nb1
    wcbf[base + 384] = b3;   // nb2_hi
    wcbf[base + 512] = b3;   // nb2_lo
}

// one wave per node; lane owns 2 dims packed in one dword (bf16 pair).
// coalesced 64-edge esrc load + readlane; 8 independent gathers per group.
template <bool OUT_F32>
__global__ __launch_bounds__(256) void k_hop(const unsigned int* __restrict__ in,
                                             void* __restrict__ outv,
                                             const int* __restrict__ off,
                                             const int* __restrict__ cnt_arr,
                                             const int* __restrict__ esrc,
                                             const float* __restrict__ deg) {
    int w = (blockIdx.x * blockDim.x + threadIdx.x) >> 6;
    int lane = threadIdx.x & 63;
    int beg = __builtin_amdgcn_readfirstlane(off[w]);
    int cnt = __builtin_amdgcn_readfirstlane(cnt_arr[w]);
    float ax = 0.f, ay = 0.f;
    for (int base = 0; base < cnt; base += 64) {
        int m = cnt - base; if (m > 64) m = 64;
        int ev = esrc[beg + base + (lane < m ? lane : 0)];
        int j = 0;
        for (; j + 8 <= m; j += 8) {
            int s0 = __builtin_amdgcn_readlane(ev, j + 0);
            int s1 = __builtin_amdgcn_readlane(ev, j + 1);
            int s2 = __builtin_amdgcn_readlane(ev, j + 2);
            int s3 = __builtin_amdgcn_readlane(ev, j + 3);
            int s4 = __builtin_amdgcn_readlane(ev, j + 4);
            int s5 = __builtin_amdgcn_readlane(ev, j + 5);
            int s6 = __builtin_amdgcn_readlane(ev, j + 6);
            int s7 = __builtin_amdgcn_readlane(ev, j + 7);
            unsigned u0 = in[(size_t)s0 * 64 + lane];
            unsigned u1 = in[(size_t)s1 * 64 + lane];
            unsigned u2 = in[(size_t)s2 * 64 + lane];
            unsigned u3 = in[(size_t)s3 * 64 + lane];
            unsigned u4 = in[(size_t)s4 * 64 + lane];
            unsigned u5 = in[(size_t)s5 * 64 + lane];
            unsigned u6 = in[(size_t)s6 * 64 + lane];
            unsigned u7 = in[(size_t)s7 * 64 + lane];
            ax += __uint_as_float(u0 << 16);  ay += __uint_as_float(u0 & 0xffff0000u);
            ax += __uint_as_float(u1 << 16);  ay += __uint_as_float(u1 & 0xffff0000u);
            ax += __uint_as_float(u2 << 16);  ay += __uint_as_float(u2 & 0xffff0000u);
            ax += __uint_as_float(u3 << 16);  ay += __uint_as_float(u3 & 0xffff0000u);
            ax += __uint_as_float(u4 << 16);  ay += __uint_as_float(u4 & 0xffff0000u);
            ax += __uint_as_float(u5 << 16);  ay += __uint_as_float(u5 & 0xffff0000u);
            ax += __uint_as_float(u6 << 16);  ay += __uint_as_float(u6 & 0xffff0000u);
            ax += __uint_as_float(u7 << 16);  ay += __uint_as_float(u7 & 0xffff0000u);
        }
        for (; j < m; ++j) {
            int s0 = __builtin_amdgcn_readlane(ev, j);
            unsigned u0 = in[(size_t)s0 * 64 + lane];
            ax += __uint_as_float(u0 << 16);  ay += __uint_as_float(u0 & 0xffff0000u);
        }
    }
    float inv = 1.0f / deg[w];
    ax *= inv; ay *= inv;
    if (OUT_F32) {
        float2 p; p.x = ax; p.y = ay;
        reinterpret_cast<float2*>(outv)[(size_t)w * 64 + lane] = p;
    } else {
        reinterpret_cast<unsigned int*>(outv)[(size_t)w * 64 + lane] =
            (unsigned)f2bf(ax) | ((unsigned)f2bf(ay) << 16);
    }
}

// MFMA GEMM (M=32/block, N=128, K=640) + fused LayerNorm.
// X = [h_hi | h_lo | nb1 | nb2_hi | nb2_lo] bf16; B-frags cached in regs per 320-K chunk.
__global__ __launch_bounds__(256) void k_gemm_ln(
    const unsigned int* __restrict__ hhi, const float* __restrict__ hf,
    const unsigned int* __restrict__ nb1u, const float* __restrict__ nb2f,
    const unsigned short* __restrict__ wcbf, const float* __restrict__ bias,
    const float* __restrict__ gamma, const float* __restrict__ beta,
    float* __restrict__ out) {
    __shared__ __align__(16) unsigned short Xs[32 * XPITCH];   // 41472 B; aliased by zs in epilogue
    __shared__ float mu_s[32], rs_s[32];
    unsigned int* Xs_u = reinterpret_cast<unsigned int*>(Xs);
    float* zs = reinterpret_cast<float*>(Xs);                  // [32][132]

    const int t = threadIdx.x;
    const int node0 = blockIdx.x * 32;

    // ---- staging: 32 rows x 64 dwords per segment ----
    #pragma unroll
    for (int it = 0; it < 8; ++it) {
        int i = t + 256 * it;
        int row = i >> 6, d = i & 63;
        size_t g = (size_t)(node0 + row) * 64 + d;
        int lb = row * XPITCH_DW + d;
        unsigned hh = hhi[g];
        Xs_u[lb] = hh;                                          // seg0: h_hi
        float2 hv = reinterpret_cast<const float2*>(hf)[g];
        unsigned lo = (unsigned)f2bf(hv.x - bf2f((unsigned short)(hh & 0xffffu)))
                    | ((unsigned)f2bf(hv.y - bf2f((unsigned short)(hh >> 16))) << 16);
        Xs_u[lb + 64] = lo;                                     // seg1: h_lo
        Xs_u[lb + 128] = nb1u[g];                               // seg2: nb1
        float2 nv = reinterpret_cast<const float2*>(nb2f)[g];
        unsigned short n0 = f2bf(nv.x), n1 = f2bf(nv.y);
        Xs_u[lb + 192] = (unsigned)n0 | ((unsigned)n1 << 16);   // seg3: nb2_hi
        Xs_u[lb + 256] = (unsigned)f2bf(nv.x - bf2f(n0))
                       | ((unsigned)f2bf(nv.y - bf2f(n1)) << 16); // seg4: nb2_lo
    }
    __syncthreads();

    const int wv = t >> 6, lane = t & 63;
    const int lm = lane & 15, quad = lane >> 4;

    f32x4 acc[2][2] = {{{0.f, 0.f, 0.f, 0.f}, {0.f, 0.f, 0.f, 0.f}},
                       {{0.f, 0.f, 0.f, 0.f}, {0.f, 0.f, 0.f, 0.f}}};

    for (int c = 0; c < 2; ++c) {
        bf16x8 bfr[2][10];
        #pragma unroll
        for (int nt = 0; nt < 2; ++nt) {
            #pragma unroll
            for (int s = 0; s < 10; ++s) {
                int o = wv * 32 + nt * 16 + lm;
                int k = c * 320 + s * 32 + quad * 8;
                bfr[nt][s] = *reinterpret_cast<const bf16x8*>(wcbf + (size_t)o * KTOT + k);
            }
        }
        #pragma unroll
        for (int s = 0; s < 10; ++s) {
            int koff = c * 320 + s * 32 + quad * 8;
            bf16x8 a0 = *reinterpret_cast<const bf16x8*>(&Xs[(0 * 16 + lm) * XPITCH + koff]);
            bf16x8 a1 = *reinterpret_cast<const bf16x8*>(&Xs[(1 * 16 + lm) * XPITCH + koff]);
            #pragma unroll
            for (int nt = 0; nt < 2; ++nt) {
                acc[0][nt] = __builtin_amdgcn_mfma_f32_16x16x32_bf16(a0, bfr[nt][s], acc[0][nt], 0, 0, 0);
                acc[1][nt] = __builtin_amdgcn_mfma_f32_16x16x32_bf16(a1, bfr[nt][s], acc[1][nt], 0, 0, 0);
            }
        }
    }
    __syncthreads();   // all waves done reading Xs before zs overwrite

    // ---- z -> LDS (add bias); C layout: col = lane&15, row = quad*4 + reg ----
    #pragma unroll
    for (int nt = 0; nt < 2; ++nt) {
        int o = wv * 32 + nt * 16 + lm;
        float bv = bias[o];
        #pragma unroll
        for (int mt = 0; mt < 2; ++mt) {
            #pragma unroll
            for (int r = 0; r < 4; ++r) {
                int m = mt * 16 + quad * 4 + r;
                zs[m * 132 + o] = acc[mt][nt][r] + bv;
            }
        }
    }
    __syncthreads();

    {   // LN stats: 8 threads per node
        int n = t >> 3, l = t & 7;
        float s = 0.f, ss = 0.f;
        #pragma unroll
        for (int q = 0; q < 16; ++q) {
            float v = zs[n * 132 + l + 8 * q];
            s += v; ss += v * v;
        }
        s += __shfl_xor(s, 1);  ss += __shfl_xor(ss, 1);
        s += __shfl_xor(s, 2);  ss += __shfl_xor(ss, 2);
        s += __shfl_xor(s, 4);  ss += __shfl_xor(ss, 4);
        if (l == 0) {
            float m = s * (1.f / 128.f);
            float var = ss * (1.f / 128.f) - m * m;
            mu_s[n] = m;
            rs_s[n] = rsqrtf(var + LN_EPS);
        }
    }
    __syncthreads();

    #pragma unroll
    for (int it = 0; it < 16; ++it) {
        int i = t + 256 * it;
        int n = i >> 7, o = i & 127;
        float v = (zs[n * 132 + o] - mu_s[n]) * rs_s[n] * gamma[o] + beta[o];
        out[(size_t)(node0 + n) * D + o] = v;
    }
}

extern "C" void kernel_launch(void* const* d_in, const int* in_sizes, int n_in,
                              void* d_out, int out_size, void* d_ws, size_t ws_size,
                              hipStream_t stream) {
    const float* h      = (const float*)d_in[0];
    const int*   ei     = (const int*)d_in[1];
    const float* deg    = (const float*)d_in[2];
    const float* Wself  = (const float*)d_in[3];
    const float* Wnb1   = (const float*)d_in[4];
    const float* Whp    = (const float*)d_in[5];
    const float* Wnb2   = (const float*)d_in[6];
    const float* bias   = (const float*)d_in[7];
    const float* logits = (const float*)d_in[8];
    const float* gamma  = (const float*)d_in[9];
    const float* beta   = (const float*)d_in[10];
    float* out = (float*)d_out;

    char* ws = (char*)d_ws;
    int* off                 = (int*)(ws + WS_OFF_OFF);
    int* cur                 = (int*)(ws + WS_OFF_CUR);
    int* bsum                = (int*)(ws + WS_OFF_BSUM);
    int* gcur                = (int*)(ws + WS_OFF_GCUR);
    unsigned short* wcbf     = (unsigned short*)(ws + WS_OFF_WCBF);
    int* esrc                = (int*)(ws + WS_OFF_ESRC);
    int2* gbuf               = (int2*)(ws + WS_OFF_GBUF);
    unsigned int* hhi        = (unsigned int*)(ws + WS_OFF_HHI);
    unsigned int* nb1u       = (unsigned int*)(ws + WS_OFF_NB1);

    const int* src = ei;
    const int* dst = ei + NE;

    hipMemsetAsync(cur, 0, NN * sizeof(int), stream);
    hipMemsetAsync(gcur, 0, NBK * sizeof(int), stream);

    k_weights<<<64, 256, 0, stream>>>(Wself, Wnb1, Whp, Wnb2, logits, wcbf);
    k_scan1<<<NSB, 256, 0, stream>>>(deg, off, bsum);
    k_scan2<<<1, 64, 0, stream>>>(bsum);
    k_scan3<<<(NN + 255) / 256, 256, 0, stream>>>(off, bsum);
    k_bin<<<(NE + 2047) / 2048, 256, 0, stream>>>(src, dst, gcur, gbuf);
    k_scatter2<<<NBK, 1024, 0, stream>>>(gbuf, gcur, off, cur, esrc);

    // prep AFTER scatter2: hhi overlays the (now dead) gbuf region
    k_prep<<<25000, 256, 0, stream>>>(h, hhi);

    // hop1: gather h_hi (bf16) -> nb1_hi (bf16, ws)
    k_hop<false><<<(NN * 64) / 256, 256, 0, stream>>>(hhi, (void*)nb1u, off, cur, esrc, deg);
    // hop2: gather nb1_hi (bf16) -> nb2 (fp32, d_out scratch; gemm reads own rows then overwrites)
    k_hop<true><<<(NN * 64) / 256, 256, 0, stream>>>(nb1u, (void*)out, off, cur, esrc, deg);

    k_gemm_ln<<<NN / 32, 256, 0, stream>>>(hhi, h, nb1u, out, wcbf, bias, gamma, beta, out);
}